// Round 8
// baseline (1348.793 us; speedup 1.0000x reference)
//
#include <hip/hip_runtime.h>
#include <hip/hip_bf16.h>
#include <math.h>

#define HH 240
#define WW 1216
#define BATCH 4
#define PROP 6
constexpr int HW = HH * WW;            // 291,840
constexpr int NPIX = BATCH * HW;       // 1,167,360
constexpr int NPART = 1024;

typedef short short8 __attribute__((ext_vector_type(8)));
typedef float floatx4 __attribute__((ext_vector_type(4)));

__device__ __forceinline__ unsigned short f2bf(float f) {
    unsigned int u = __float_as_uint(f);
    unsigned int r = (u + 0x7FFFu + ((u >> 16) & 1u)) >> 16;
    return (unsigned short)r;
}
__device__ __forceinline__ float bf2f(unsigned short h) {
    return __uint_as_float(((unsigned int)h) << 16);
}

// LDS layout (bytes):
//   gs16   [8][10][66] u16 (bf16-hi guidance)  @ 0     : 10560
//   region2 @ 10560:
//     wst  [32][96] f32 (12288; dead after A-frag build)
//     offtab [96] u32 @ 22848 (384; dead after cvaddr build)
//     ct   4 waves x [64][25] f32 (25600; written after sync2 - aliases both)
//   ftile  [16][72] f32 (feat tile, rows y0t-4..+11, cols x0-4..+67)
//          @ 36160 : 4608
constexpr int CT_STRIDE = 25;          // gcd(25,32)=1 -> conflict-free
constexpr int SMEM_BYTES = 40768;      // 4 blocks/CU (<= 40960)

// ---------------------------------------------------------------------------
// Propagation v7: affinity conv (25x72) on MFMA (guidance bf16-hi, weights
// hi/lo 2-term). Bilinear gather served from a feat LDS tile (offsets are
// small: sigma~0.42); exact global clamp path for rare out-of-tile lanes.
// ---------------------------------------------------------------------------
__global__ __launch_bounds__(256, 4) void prop_kernel(
    const float* __restrict__ featPrev,   // [B][HW]
    const float* __restrict__ gbase,      // guidance + 8k*HW; batch stride 48*HW
    const float* __restrict__ aw,         // [9][8][3][3]
    const float* __restrict__ ab,         // [9]
    const float* __restrict__ ow,         // [16][8][3][3]
    const float* __restrict__ ob,         // [16]
    const float* __restrict__ w3,         // [9]
    const float* __restrict__ b3,         // [1]
    float* __restrict__ featNext)         // [B][HW]
{
    __shared__ __attribute__((aligned(16))) unsigned char smem[SMEM_BYTES];
    unsigned short* gs16 = (unsigned short*)smem;
    float*    wst    = (float*)(smem + 10560);
    uint32_t* offtab = (uint32_t*)(smem + 22848);
    float*    ctb    = (float*)(smem + 10560);
    float*    ftile  = (float*)(smem + 36160);

    const int tid = threadIdx.x;
    const int x0 = blockIdx.x * 64;
    const int y0t = blockIdx.y * 8;
    const int b = blockIdx.z;
    const float* gb = gbase + (size_t)b * (48 * HW);
    const float* fb = featPrev + (size_t)b * HW;

    // ---- stage guidance ext tile as bf16-hi u16 (zero-pad OOB) ----
    for (int idx = tid; idx < 5280; idx += 256) {
        const int c = idx / 660, rem = idx - c * 660;
        const int row = rem / 66, col = rem - row * 66;
        const int gy = y0t + row - 1, gx = x0 + col - 1;
        float v = 0.0f;
        if (((unsigned)gy < (unsigned)HH) & ((unsigned)gx < (unsigned)WW))
            v = gb[c * HW + gy * WW + gx];
        gs16[idx] = f2bf(v);
    }
    // ---- stage feat tile (clamp-replicated; exact fp32) ----
    for (int idx = tid; idx < 16 * 72; idx += 256) {
        const int r = idx / 72, cc = idx - r * 72;
        const int gy = min(max(y0t - 4 + r, 0), HH - 1);
        const int gx = min(max(x0 - 4 + cc, 0), WW - 1);
        ftile[idx] = fb[gy * WW + gx];
    }
    // ---- stage weight matrix [o(32,pad)][k(96,pad)] fp32, zeros on pad ----
    for (int idx = tid; idx < 3072; idx += 256) {
        const int o = idx / 96, k = idx - o * 96;
        float v = 0.0f;
        if (o < 25 && k < 72) {
            const int c = k / 9, t = k - 9 * c;
            v = (o < 9) ? aw[(o * 8 + c) * 9 + t] : ow[((o - 9) * 8 + c) * 9 + t];
        }
        wst[idx] = v;
    }
    // ---- offtab[s][e][g]: gs16 element-offset of (c, dy, dx) for that k ----
    if (tid < 96) {
        const int s = tid >> 5, rem = tid & 31, e = rem >> 2, gq = rem & 3;
        const int k = s * 32 + gq * 8 + e;
        uint32_t off = 0;
        if (k < 72) {
            const int c = k / 9, t = k - 9 * c, dy = t / 3, dx = t - 3 * dy;
            off = (uint32_t)(c * 660 + dy * 66 + dx);
        }
        offtab[tid] = off;
    }
    __syncthreads();

    const int lane = tid & 63, wid = tid >> 6;
    const int grp = lane >> 4, l15 = lane & 15;

    // ---- A fragments: lane supplies A[m = l15][k = s*32 + grp*8 + e] ----
    short8 Ah0[3], Ah1[3], Al0[3], Al1[3];
    {
        const int kb = grp * 8;
#pragma unroll
        for (int s = 0; s < 3; ++s) {
            const float* wp0 = &wst[l15 * 96 + s * 32 + kb];
            const float* wp1 = &wst[(16 + l15) * 96 + s * 32 + kb];
            short8 h0, l0, h1, l1;
#pragma unroll
            for (int e = 0; e < 8; ++e) {
                const float v0 = wp0[e];
                const unsigned short hb0 = f2bf(v0);
                h0[e] = (short)hb0;
                l0[e] = (short)f2bf(v0 - bf2f(hb0));
                const float v1 = wp1[e];
                const unsigned short hb1 = f2bf(v1);
                h1[e] = (short)hb1;
                l1[e] = (short)f2bf(v1 - bf2f(hb1));
            }
            Ah0[s] = h0; Al0[s] = l0; Ah1[s] = h1; Al1[s] = l1;
        }
    }

    // ---- per-lane B-read byte addresses (24) ----
    uint32_t cvaddr[3][8];
#pragma unroll
    for (int s = 0; s < 3; ++s)
#pragma unroll
        for (int e = 0; e < 8; ++e)
            cvaddr[s][e] = (offtab[s * 32 + e * 4 + grp] +
                            (uint32_t)(wid * 132 + l15)) * 2u;

    // ---- uniform epilogue params (s_loads) ----
    float abv[9], w3v[9], obv[16];
#pragma unroll
    for (int t = 0; t < 9; ++t) { abv[t] = ab[t]; w3v[t] = w3[t]; }
#pragma unroll
    for (int o = 0; o < 16; ++o) obv[o] = ob[o];
    const float b3v = b3[0];

    __syncthreads();   // all waves done reading wst/offtab before ct reuse

    float* ct = ctb + wid * (64 * CT_STRIDE);
    const int ybase = y0t + wid * 2;
    const unsigned char* gsB = (const unsigned char*)gs16;

#pragma unroll 1
    for (int r = 0; r < 2; ++r) {
        const int y = ybase + r;
        // ---- 4 MFMA chunks back-to-back: conv outputs for the 64-px row ----
#pragma unroll
        for (int ch = 0; ch < 4; ++ch) {
            floatx4 acc0 = {0.f, 0.f, 0.f, 0.f};
            floatx4 acc1 = {0.f, 0.f, 0.f, 0.f};
#pragma unroll
            for (int s = 0; s < 3; ++s) {
                uint32_t ev[8];
#pragma unroll
                for (int e = 0; e < 8; ++e)
                    ev[e] = *(const unsigned short*)(gsB + cvaddr[s][e] +
                                                     (r * 66 + ch * 16) * 2);
                union { uint32_t u[4]; short8 v; } bh;
#pragma unroll
                for (int i = 0; i < 4; ++i)
                    bh.u[i] = ev[2 * i] | (ev[2 * i + 1] << 16);
                acc0 = __builtin_amdgcn_mfma_f32_16x16x32_bf16(Ah0[s], bh.v, acc0, 0, 0, 0);
                acc1 = __builtin_amdgcn_mfma_f32_16x16x32_bf16(Ah1[s], bh.v, acc1, 0, 0, 0);
                acc0 = __builtin_amdgcn_mfma_f32_16x16x32_bf16(Al0[s], bh.v, acc0, 0, 0, 0);
                acc1 = __builtin_amdgcn_mfma_f32_16x16x32_bf16(Al1[s], bh.v, acc1, 0, 0, 0);
            }
            // C layout: col(px) = l15, row(o) = grp*4 + i  (+16 for Mtile1)
            const int pxb = (ch * 16 + l15) * CT_STRIDE;
#pragma unroll
            for (int i = 0; i < 4; ++i) {
                ct[pxb + grp * 4 + i] = acc0[i];
                if (grp * 4 + i < 9)                    // only o=16..24 valid
                    ct[pxb + 16 + grp * 4 + i] = acc1[i];
            }
        }

        // ---- epilogue: lane owns pixel x0+lane of row y ----
        const float* cb = ct + lane * CT_STRIDE;
        float av[25];
#pragma unroll
        for (int o = 0; o < 25; ++o) av[o] = cb[o];

        float wg[9], wsum = 1e-8f;
#pragma unroll
        for (int t = 0; t < 9; ++t) {
            const float s = 1.0f / (1.0f + __expf(-(av[t] + abv[t])));
            wg[t] = s;
            wsum += s;
        }
        const float winv = 1.0f / wsum;
        const int x = x0 + lane;

        float sum = 0.0f;
#pragma unroll
        for (int t = 0; t < 9; ++t) {
            float oy, ox;
            if (t < 4)       { oy = av[9 + 2 * t] + obv[2 * t];
                               ox = av[10 + 2 * t] + obv[2 * t + 1]; }
            else if (t == 4) { oy = 0.0f; ox = 0.0f; }
            else             { oy = av[7 + 2 * t] + obv[2 * t - 2];
                               ox = av[8 + 2 * t] + obv[2 * t - 1]; }

            const float py = (float)(y - 1 + (t / 3)) + oy;
            const float px = (float)(x - 1 + (t % 3)) + ox;
            const float fy = floorf(py), fx = floorf(px);
            const float wy = py - fy, wx = px - fx;
            const int iy = (int)fy, ix = (int)fx;
            const int iy1 = iy + 1, ix1 = ix + 1;

            const bool vy0 = (unsigned)iy < (unsigned)HH;
            const bool vy1 = (unsigned)iy1 < (unsigned)HH;
            const bool vx0 = (unsigned)ix < (unsigned)WW;
            const bool vx1 = (unsigned)ix1 < (unsigned)WW;
            const float wy0 = 1.0f - wy, wx0 = 1.0f - wx;

            // tile-local coords; in-tile iff the 2x2 footprint is inside
            const int lyt = iy - (y0t - 4);
            const int lxt = ix - (x0 - 4);
            const bool in_tile = ((unsigned)lyt < 15u) & ((unsigned)lxt < 71u);

            float v00, v01, v10, v11;
            if (in_tile) {
                const float* tp = &ftile[lyt * 72 + lxt];
                v00 = tp[0];  v01 = tp[1];
                v10 = tp[72]; v11 = tp[73];
            } else {
                const int ry0 = min(max(iy, 0), HH - 1) * WW;
                const int ry1 = min(max(iy1, 0), HH - 1) * WW;
                const int cx0 = min(max(ix, 0), WW - 1);
                const int cx1 = min(max(ix1, 0), WW - 1);
                v00 = fb[ry0 + cx0]; v01 = fb[ry0 + cx1];
                v10 = fb[ry1 + cx0]; v11 = fb[ry1 + cx1];
            }

            float s = 0.0f;
            s = fmaf((vy0 & vx0) ? wy0 * wx0 : 0.0f, v00, s);
            s = fmaf((vy0 & vx1) ? wy0 * wx  : 0.0f, v01, s);
            s = fmaf((vy1 & vx0) ? wy  * wx0 : 0.0f, v10, s);
            s = fmaf((vy1 & vx1) ? wy  * wx  : 0.0f, v11, s);

            sum = fmaf(wg[t] * w3v[t], s, sum);
        }
        featNext[(size_t)b * HW + (size_t)y * WW + x] = fmaf(winv, sum, b3v);
    }
}

// ---------------------------------------------------------------------------
// Stage 1 of BN stats: per-block partial sums (float4-vectorized).
// ---------------------------------------------------------------------------
__global__ __launch_bounds__(256) void stats_part(
    const float* __restrict__ y0s, const float* __restrict__ y1s,
    const float* __restrict__ y2s, float* __restrict__ part)
{
    float a[9] = {0, 0, 0, 0, 0, 0, 0, 0, 0};
    const int n4 = NPIX / 4;
    const int stride = gridDim.x * 256;
    for (int i = blockIdx.x * 256 + threadIdx.x; i < n4; i += stride) {
        const float4 q0 = ((const float4*)y0s)[i];
        const float4 q1 = ((const float4*)y1s)[i];
        const float4 q2 = ((const float4*)y2s)[i];
        const float v0s[4] = {q0.x, q0.y, q0.z, q0.w};
        const float v1s[4] = {q1.x, q1.y, q1.z, q1.w};
        const float v2s[4] = {q2.x, q2.y, q2.z, q2.w};
#pragma unroll
        for (int j = 0; j < 4; ++j) {
            const float v0 = v0s[j], v1 = v1s[j], v2 = v2s[j];
            a[0] += v0; a[1] += v1; a[2] += v2;
            a[3] = fmaf(v0, v0, a[3]); a[4] = fmaf(v0, v1, a[4]);
            a[5] = fmaf(v0, v2, a[5]); a[6] = fmaf(v1, v1, a[6]);
            a[7] = fmaf(v1, v2, a[7]); a[8] = fmaf(v2, v2, a[8]);
        }
    }
    __shared__ float red[4][9];
    const int lane = threadIdx.x & 63, wv = threadIdx.x >> 6;
#pragma unroll
    for (int q = 0; q < 9; ++q) {
        float v = a[q];
        for (int o = 32; o; o >>= 1) v += __shfl_down(v, o, 64);
        if (lane == 0) red[wv][q] = v;
    }
    __syncthreads();
    if (threadIdx.x < 9) {
        const int q = threadIdx.x;
        part[blockIdx.x * 9 + q] = red[0][q] + red[1][q] + red[2][q] + red[3][q];
    }
}

// ---------------------------------------------------------------------------
// Stage 2: finalize per-channel BN scale/shift for sf = proj(y).
// ---------------------------------------------------------------------------
__global__ __launch_bounds__(256) void stats_final(
    const float* __restrict__ part, const float* __restrict__ proj_w,
    const float* __restrict__ bn_g, const float* __restrict__ bn_b,
    float* __restrict__ stats)
{
    float a[9] = {0, 0, 0, 0, 0, 0, 0, 0, 0};
    for (int i = threadIdx.x; i < NPART; i += 256) {
#pragma unroll
        for (int q = 0; q < 9; ++q) a[q] += part[i * 9 + q];
    }
    __shared__ float red[4][9];
    const int lane = threadIdx.x & 63, wv = threadIdx.x >> 6;
#pragma unroll
    for (int q = 0; q < 9; ++q) {
        float v = a[q];
        for (int o = 32; o; o >>= 1) v += __shfl_down(v, o, 64);
        if (lane == 0) red[wv][q] = v;
    }
    __syncthreads();
    if (threadIdx.x == 0) {
        float s[9];
#pragma unroll
        for (int q = 0; q < 9; ++q) s[q] = red[0][q] + red[1][q] + red[2][q] + red[3][q];
        const float invN = 1.0f / (float)NPIX;
        const float m0 = s[0] * invN, m1 = s[1] * invN, m2 = s[2] * invN;
        const float E00 = s[3] * invN, E01 = s[4] * invN, E02 = s[5] * invN;
        const float E11 = s[6] * invN, E12 = s[7] * invN, E22 = s[8] * invN;
#pragma unroll
        for (int c = 0; c < 6; ++c) {
            const float p0 = proj_w[c * 3], p1 = proj_w[c * 3 + 1], p2 = proj_w[c * 3 + 2];
            const float mu = p0 * m0 + p1 * m1 + p2 * m2;
            const float e2 = p0 * p0 * E00 + p1 * p1 * E11 + p2 * p2 * E22 +
                             2.0f * (p0 * p1 * E01 + p0 * p2 * E02 + p1 * p2 * E12);
            const float var = e2 - mu * mu;
            const float sc = bn_g[c] / sqrtf(var + 1e-5f);
            stats[c] = sc;
            stats[6 + c] = bn_b[c] - mu * sc;
        }
    }
}

// ---------------------------------------------------------------------------
// Fused head (unchanged): float4 phase-1, XCD-swizzled grid, a1/a2 in regs.
// ---------------------------------------------------------------------------
constexpr int HB_X = WW / 32;          // 38
constexpr int HB_Y = HH / 8;           // 30
constexpr int HB_N = HB_X * HB_Y * BATCH;   // 4560 (divisible by 8)
constexpr int HB_CHUNK = HB_N / 8;     // 570

__global__ __launch_bounds__(256, 4) void head_kernel(
    const float* __restrict__ y0s, const float* __restrict__ y1s,
    const float* __restrict__ y2s, const float* __restrict__ attn,
    const float* __restrict__ stats,   // scale[6], shift[6]
    const float* __restrict__ proj_w,
    const float* __restrict__ c0_w, const float* __restrict__ c0_b,
    const float* __restrict__ cs_w, const float* __restrict__ cs_b,
    const float* __restrict__ c1_w, const float* __restrict__ c1_b,
    const float* __restrict__ c2_w, const float* __restrict__ c2_b,
    const float* __restrict__ csq_w, const float* __restrict__ csq_b,
    const float* __restrict__ cv_w, const float* __restrict__ cv_b,
    float* __restrict__ out)
{
    __shared__ float ap[22][432];    // a1_pre, ext tile 12x36 (halo 2)
    __shared__ float aggs[2][340];   // agg, tile+halo1 10x34

    const int tid = threadIdx.x;
    const int bid = blockIdx.x;
    const int swz = (bid & 7) * HB_CHUNK + (bid >> 3);
    const int b = swz / (HB_X * HB_Y);
    const int rem0 = swz - b * (HB_X * HB_Y);
    const int by = rem0 / HB_X;
    const int bx = rem0 - by * HB_X;
    const int x0 = bx * 32;
    const int y0t = by * 8;

    // ---- phase 1: a1_pre over ext tile, float4 jobs ----
    for (int job = tid; job < 2040; job += 256) {
        int c = 0, rr, xc;
        bool isY;
        if (job < 1920) {
            c = job / 120;
            const int rem = job - c * 120;
            rr = rem / 10; xc = rem - rr * 10;
            isY = false;
        } else {
            const int rem = job - 1920;
            rr = rem / 10; xc = rem - rr * 10;
            isY = true;
        }
        const int gy = y0t + rr - 2;
        const int gxb = x0 - 4 + 4 * xc;           // 16B-aligned
        const bool gok = ((unsigned)gy < (unsigned)HH) &
                         ((unsigned)gxb <= (unsigned)(WW - 4));
        const size_t prow = (size_t)gy * WW + gxb;

        if (!isY) {
            float4 v4 = {0.f, 0.f, 0.f, 0.f};
            if (gok)
                v4 = *(const float4*)&attn[(size_t)b * 16 * HW + (size_t)c * HW + prow];
            const float w = c0_w[c], bb = c0_b[c];
            const float vin[4] = {v4.x, v4.y, v4.z, v4.w};
#pragma unroll
            for (int j = 0; j < 4; ++j) {
                const int exl = 4 * xc - 2 + j;
                if ((unsigned)exl < 36u)
                    ap[c][rr * 36 + exl] = gok ? fmaf(w, vin[j], bb) : 0.0f;
            }
        } else {
            float4 q0 = {0.f, 0.f, 0.f, 0.f}, q1 = q0, q2 = q0;
            if (gok) {
                const size_t p = (size_t)b * HW + prow;
                q0 = *(const float4*)&y0s[p];
                q1 = *(const float4*)&y1s[p];
                q2 = *(const float4*)&y2s[p];
            }
            const float v0s[4] = {q0.x, q0.y, q0.z, q0.w};
            const float v1s[4] = {q1.x, q1.y, q1.z, q1.w};
            const float v2s[4] = {q2.x, q2.y, q2.z, q2.w};
#pragma unroll
            for (int j = 0; j < 4; ++j) {
                const int exl = 4 * xc - 2 + j;
                if ((unsigned)exl >= 36u) continue;
#pragma unroll
                for (int q = 0; q < 6; ++q) {
                    float v = 0.0f;
                    if (gok) {
                        const float sraw = proj_w[q * 3] * v0s[j] +
                                           proj_w[q * 3 + 1] * v1s[j] +
                                           proj_w[q * 3 + 2] * v2s[j];
                        float sf = fmaf(stats[q], sraw, stats[6 + q]);
                        sf = sf > 0.0f ? sf : 0.2f * sf;
                        v = fmaf(c0_w[16 + q], sf, c0_b[16 + q]);
                    }
                    ap[16 + q][rr * 36 + exl] = v;
                }
            }
        }
    }
    __syncthreads();

    auto compute_px = [&](int ay, int ax, float* a1, float* a2) {
        const int ey = ay + 1, ex = ax + 1;   // ext coords
#pragma unroll
        for (int j = 0; j < 11; ++j) { a1[j] = c1_b[j]; a2[j] = c2_b[j]; }
#pragma unroll
        for (int c = 0; c < 22; ++c) {
            float dw = cs_b[c];
            float ctr = 0.0f;
#pragma unroll
            for (int t = 0; t < 9; ++t) {
                const float av = ap[c][(ey + t / 3 - 1) * 36 + (ex + t % 3 - 1)];
                dw = fmaf(cs_w[c * 9 + t], av, dw);
                if (t == 4) ctr = av;
            }
#pragma unroll
            for (int j = 0; j < 11; ++j) {
                a1[j] = fmaf(c1_w[j * 22 + c], ctr, a1[j]);
                a2[j] = fmaf(c2_w[j * 22 + c], dw, a2[j]);
            }
        }
    };

    // ---- phase 2a: ring jobs (84 halo pixels of the 10x34 agg region) ----
    if (tid < 84) {
        int ay, ax;
        if (tid < 34)      { ay = 0; ax = tid; }
        else if (tid < 68) { ay = 9; ax = tid - 34; }
        else { const int s = tid - 68; ay = 1 + (s >> 1); ax = (s & 1) ? 33 : 0; }
        const int gy = y0t + ay - 1, gx = x0 + ax - 1;
        float m0 = 0.0f, m1 = 0.0f;
        if (((unsigned)gy < (unsigned)HH) & ((unsigned)gx < (unsigned)WW)) {
            float a1h[11], a2h[11];
            compute_px(ay, ax, a1h, a2h);
            float s = 0.0f, mx = -INFINITY;
#pragma unroll
            for (int j = 0; j < 11; ++j) {
                s += a1h[j] + a2h[j];
                mx = fmaxf(mx, fmaxf(a1h[j], a2h[j]));
            }
            m0 = s * (1.0f / 22.0f);
            m1 = mx;
        }
        aggs[0][ay * 34 + ax] = m0;
        aggs[1][ay * 34 + ax] = m1;
    }

    // ---- phase 2b: center pixel, keep a1/a2 in registers ----
    const int ty = tid >> 5, tx = tid & 31;
    const int ay = ty + 1, ax = tx + 1;
    float a1[11], a2[11];
    compute_px(ay, ax, a1, a2);
    {
        float s = 0.0f, mx = -INFINITY;
#pragma unroll
        for (int j = 0; j < 11; ++j) {
            s += a1[j] + a2[j];
            mx = fmaxf(mx, fmaxf(a1[j], a2[j]));
        }
        aggs[0][ay * 34 + ax] = s * (1.0f / 22.0f);
        aggs[1][ay * 34 + ax] = mx;
    }
    __syncthreads();

    // ---- phase 3: sigmoid gate + cv + final dot with y ----
    float z0 = csq_b[0], z1 = csq_b[1];
#pragma unroll
    for (int t = 0; t < 9; ++t) {
        const int ai = (ay + t / 3 - 1) * 34 + (ax + t % 3 - 1);
        const float g0 = aggs[0][ai], g1 = aggs[1][ai];
        z0 = fmaf(csq_w[t], g0, fmaf(csq_w[9 + t], g1, z0));
        z1 = fmaf(csq_w[18 + t], g0, fmaf(csq_w[27 + t], g1, z1));
    }
    const float s0 = 1.0f / (1.0f + __expf(-z0));
    const float s1 = 1.0f / (1.0f + __expf(-z1));
    float v0 = cv_b[0], v1 = cv_b[1], v2 = cv_b[2];
#pragma unroll
    for (int j = 0; j < 11; ++j) {
        const float av = a1[j] * s0 + a2[j] * s1;
        v0 = fmaf(cv_w[j], av, v0);
        v1 = fmaf(cv_w[11 + j], av, v1);
        v2 = fmaf(cv_w[22 + j], av, v2);
    }
    const size_t p = (size_t)b * HW + (size_t)(y0t + ty) * WW + (x0 + tx);
    out[p] = y0s[p] * v0 + y1s[p] * v1 + y2s[p] * v2;
}

// ---------------------------------------------------------------------------
extern "C" void kernel_launch(void* const* d_in, const int* in_sizes, int n_in,
                              void* d_out, int out_size, void* d_ws, size_t ws_size,
                              hipStream_t stream)
{
    (void)in_sizes; (void)n_in; (void)out_size; (void)ws_size;
    const float* feat_init = (const float*)d_in[0];
    const float* guidance  = (const float*)d_in[1];
    const float* attn      = (const float*)d_in[2];
    const float* aff_w_w   = (const float*)d_in[4];
    const float* aff_w_b   = (const float*)d_in[5];
    const float* aff_o_w   = (const float*)d_in[6];
    const float* aff_o_b   = (const float*)d_in[7];
    const float* w3        = (const float*)d_in[8];
    const float* b3        = (const float*)d_in[9];
    const float* proj_w    = (const float*)d_in[10];
    const float* bn_g      = (const float*)d_in[11];
    const float* bn_b      = (const float*)d_in[12];
    const float* c0_w      = (const float*)d_in[13];
    const float* c0_b      = (const float*)d_in[14];
    const float* cs_w      = (const float*)d_in[15];
    const float* cs_b      = (const float*)d_in[16];
    const float* c1_w      = (const float*)d_in[17];
    const float* c1_b      = (const float*)d_in[18];
    const float* c2_w      = (const float*)d_in[19];
    const float* c2_b      = (const float*)d_in[20];
    const float* csq_w     = (const float*)d_in[21];
    const float* csq_b     = (const float*)d_in[22];
    const float* cv_w      = (const float*)d_in[23];
    const float* cv_b      = (const float*)d_in[24];

    float* ws = (float*)d_ws;
    float* slot[5];
    for (int i = 0; i < 5; ++i) slot[i] = ws + (size_t)i * NPIX;
    float* part  = ws + (size_t)5 * NPIX;
    float* stats = part + (size_t)9 * NPART;

    const dim3 blk(256);
    const dim3 gp(WW / 64, HH / 8, BATCH);

    // propagation chain; keep feats[3],[4],[5] in slots 2,3,4
    const int dst_ids[PROP] = {0, 1, 0, 2, 3, 4};
    const float* src = feat_init;
    for (int k = 0; k < PROP; ++k) {
        float* dst = slot[dst_ids[k]];
        prop_kernel<<<gp, blk, 0, stream>>>(
            src, guidance + (size_t)8 * k * HW,
            aff_w_w + (size_t)k * 648, aff_w_b + (size_t)k * 9,
            aff_o_w + (size_t)k * 1152, aff_o_b + (size_t)k * 16,
            w3, b3, dst);
        src = dst;
    }

    stats_part<<<dim3(NPART), blk, 0, stream>>>(slot[2], slot[3], slot[4], part);
    stats_final<<<dim3(1), blk, 0, stream>>>(part, proj_w, bn_g, bn_b, stats);

    head_kernel<<<dim3(HB_N), blk, 0, stream>>>(
        slot[2], slot[3], slot[4], attn, stats, proj_w,
        c0_w, c0_b, cs_w, cs_b, c1_w, c1_b, c2_w, c2_b,
        csq_w, csq_b, cv_w, cv_b, (float*)d_out);
}

// Round 9
// 906.188 us; speedup vs baseline: 1.4884x; 1.4884x over previous
//
#include <hip/hip_runtime.h>
#include <hip/hip_bf16.h>
#include <math.h>

#define HH 240
#define WW 1216
#define BATCH 4
#define PROP 6
constexpr int HW = HH * WW;            // 291,840
constexpr int NPIX = BATCH * HW;       // 1,167,360
constexpr int NPART = 1024;

typedef short short8 __attribute__((ext_vector_type(8)));
typedef float floatx4 __attribute__((ext_vector_type(4)));

__device__ __forceinline__ unsigned short f2bf(float f) {
    unsigned int u = __float_as_uint(f);
    unsigned int r = (u + 0x7FFFu + ((u >> 16) & 1u)) >> 16;
    return (unsigned short)r;
}
__device__ __forceinline__ float bf2f(unsigned short h) {
    return __uint_as_float(((unsigned int)h) << 16);
}

// LDS layout (bytes):
//   gs16   [8][10][66] u16 (bf16-hi guidance)  @ 0     : 10560
//   region2 @ 10560:
//     wst  [32][96] f32 (12288; dead after A-frag build)
//     offtab [96] u32 @ 22848 (384; dead after cvaddr build)
//     ct   4 waves x [64][25] f32 (25600; written after sync2 - aliases both)
//   ftile  [16][72] f32 (feat tile, rows y0t-4..+11, cols x0-4..+67)
//          @ 36160 : 4608
constexpr int CT_STRIDE = 25;          // gcd(25,32)=1 -> conflict-free
constexpr int SMEM_BYTES = 40768;      // 4 blocks/CU (<= 40960)

// ---------------------------------------------------------------------------
// Propagation v8: affinity conv (25x72) on MFMA (guidance bf16-hi, weights
// hi/lo 2-term). Bilinear gather from feat LDS tile behind a WAVE-UNIFORM
// __all(in_tile) branch (scalar s_cbranch, no divergent two-sided codegen);
// whole-wave exact global clamp fallback for the astronomically rare case.
// ---------------------------------------------------------------------------
__global__ __launch_bounds__(256, 4) void prop_kernel(
    const float* __restrict__ featPrev,   // [B][HW]
    const float* __restrict__ gbase,      // guidance + 8k*HW; batch stride 48*HW
    const float* __restrict__ aw,         // [9][8][3][3]
    const float* __restrict__ ab,         // [9]
    const float* __restrict__ ow,         // [16][8][3][3]
    const float* __restrict__ ob,         // [16]
    const float* __restrict__ w3,         // [9]
    const float* __restrict__ b3,         // [1]
    float* __restrict__ featNext)         // [B][HW]
{
    __shared__ __attribute__((aligned(16))) unsigned char smem[SMEM_BYTES];
    unsigned short* gs16 = (unsigned short*)smem;
    float*    wst    = (float*)(smem + 10560);
    uint32_t* offtab = (uint32_t*)(smem + 22848);
    float*    ctb    = (float*)(smem + 10560);
    float*    ftile  = (float*)(smem + 36160);

    const int tid = threadIdx.x;
    const int x0 = blockIdx.x * 64;
    const int y0t = blockIdx.y * 8;
    const int b = blockIdx.z;
    const float* gb = gbase + (size_t)b * (48 * HW);
    const float* fb = featPrev + (size_t)b * HW;

    // ---- stage guidance ext tile as bf16-hi u16 (zero-pad OOB) ----
    for (int idx = tid; idx < 5280; idx += 256) {
        const int c = idx / 660, rem = idx - c * 660;
        const int row = rem / 66, col = rem - row * 66;
        const int gy = y0t + row - 1, gx = x0 + col - 1;
        float v = 0.0f;
        if (((unsigned)gy < (unsigned)HH) & ((unsigned)gx < (unsigned)WW))
            v = gb[c * HW + gy * WW + gx];
        gs16[idx] = f2bf(v);
    }
    // ---- stage feat tile (clamp-replicated; exact fp32) ----
    for (int idx = tid; idx < 16 * 72; idx += 256) {
        const int r = idx / 72, cc = idx - r * 72;
        const int gy = min(max(y0t - 4 + r, 0), HH - 1);
        const int gx = min(max(x0 - 4 + cc, 0), WW - 1);
        ftile[idx] = fb[gy * WW + gx];
    }
    // ---- stage weight matrix [o(32,pad)][k(96,pad)] fp32, zeros on pad ----
    for (int idx = tid; idx < 3072; idx += 256) {
        const int o = idx / 96, k = idx - o * 96;
        float v = 0.0f;
        if (o < 25 && k < 72) {
            const int c = k / 9, t = k - 9 * c;
            v = (o < 9) ? aw[(o * 8 + c) * 9 + t] : ow[((o - 9) * 8 + c) * 9 + t];
        }
        wst[idx] = v;
    }
    // ---- offtab[s][e][g]: gs16 element-offset of (c, dy, dx) for that k ----
    if (tid < 96) {
        const int s = tid >> 5, rem = tid & 31, e = rem >> 2, gq = rem & 3;
        const int k = s * 32 + gq * 8 + e;
        uint32_t off = 0;
        if (k < 72) {
            const int c = k / 9, t = k - 9 * c, dy = t / 3, dx = t - 3 * dy;
            off = (uint32_t)(c * 660 + dy * 66 + dx);
        }
        offtab[tid] = off;
    }
    __syncthreads();

    const int lane = tid & 63, wid = tid >> 6;
    const int grp = lane >> 4, l15 = lane & 15;

    // ---- A fragments: lane supplies A[m = l15][k = s*32 + grp*8 + e] ----
    short8 Ah0[3], Ah1[3], Al0[3], Al1[3];
    {
        const int kb = grp * 8;
#pragma unroll
        for (int s = 0; s < 3; ++s) {
            const float* wp0 = &wst[l15 * 96 + s * 32 + kb];
            const float* wp1 = &wst[(16 + l15) * 96 + s * 32 + kb];
            short8 h0, l0, h1, l1;
#pragma unroll
            for (int e = 0; e < 8; ++e) {
                const float v0 = wp0[e];
                const unsigned short hb0 = f2bf(v0);
                h0[e] = (short)hb0;
                l0[e] = (short)f2bf(v0 - bf2f(hb0));
                const float v1 = wp1[e];
                const unsigned short hb1 = f2bf(v1);
                h1[e] = (short)hb1;
                l1[e] = (short)f2bf(v1 - bf2f(hb1));
            }
            Ah0[s] = h0; Al0[s] = l0; Ah1[s] = h1; Al1[s] = l1;
        }
    }

    // ---- per-lane B-read byte addresses (24) ----
    uint32_t cvaddr[3][8];
#pragma unroll
    for (int s = 0; s < 3; ++s)
#pragma unroll
        for (int e = 0; e < 8; ++e)
            cvaddr[s][e] = (offtab[s * 32 + e * 4 + grp] +
                            (uint32_t)(wid * 132 + l15)) * 2u;

    // ---- uniform epilogue params (s_loads) ----
    float abv[9], w3v[9], obv[16];
#pragma unroll
    for (int t = 0; t < 9; ++t) { abv[t] = ab[t]; w3v[t] = w3[t]; }
#pragma unroll
    for (int o = 0; o < 16; ++o) obv[o] = ob[o];
    const float b3v = b3[0];

    __syncthreads();   // all waves done reading wst/offtab before ct reuse

    float* ct = ctb + wid * (64 * CT_STRIDE);
    const int ybase = y0t + wid * 2;
    const unsigned char* gsB = (const unsigned char*)gs16;

#pragma unroll 1
    for (int r = 0; r < 2; ++r) {
        const int y = ybase + r;
        // ---- 4 MFMA chunks back-to-back: conv outputs for the 64-px row ----
#pragma unroll
        for (int ch = 0; ch < 4; ++ch) {
            floatx4 acc0 = {0.f, 0.f, 0.f, 0.f};
            floatx4 acc1 = {0.f, 0.f, 0.f, 0.f};
#pragma unroll
            for (int s = 0; s < 3; ++s) {
                uint32_t ev[8];
#pragma unroll
                for (int e = 0; e < 8; ++e)
                    ev[e] = *(const unsigned short*)(gsB + cvaddr[s][e] +
                                                     (r * 66 + ch * 16) * 2);
                union { uint32_t u[4]; short8 v; } bh;
#pragma unroll
                for (int i = 0; i < 4; ++i)
                    bh.u[i] = ev[2 * i] | (ev[2 * i + 1] << 16);
                acc0 = __builtin_amdgcn_mfma_f32_16x16x32_bf16(Ah0[s], bh.v, acc0, 0, 0, 0);
                acc1 = __builtin_amdgcn_mfma_f32_16x16x32_bf16(Ah1[s], bh.v, acc1, 0, 0, 0);
                acc0 = __builtin_amdgcn_mfma_f32_16x16x32_bf16(Al0[s], bh.v, acc0, 0, 0, 0);
                acc1 = __builtin_amdgcn_mfma_f32_16x16x32_bf16(Al1[s], bh.v, acc1, 0, 0, 0);
            }
            // C layout: col(px) = l15, row(o) = grp*4 + i  (+16 for Mtile1)
            const int pxb = (ch * 16 + l15) * CT_STRIDE;
#pragma unroll
            for (int i = 0; i < 4; ++i) {
                ct[pxb + grp * 4 + i] = acc0[i];
                if (grp * 4 + i < 9)                    // only o=16..24 valid
                    ct[pxb + 16 + grp * 4 + i] = acc1[i];
            }
        }

        // ---- epilogue: lane owns pixel x0+lane of row y ----
        const float* cb = ct + lane * CT_STRIDE;
        float av[25];
#pragma unroll
        for (int o = 0; o < 25; ++o) av[o] = cb[o];

        float wg[9], wsum = 1e-8f;
#pragma unroll
        for (int t = 0; t < 9; ++t) {
            const float s = 1.0f / (1.0f + __expf(-(av[t] + abv[t])));
            wg[t] = s;
            wsum += s;
        }
        const float winv = 1.0f / wsum;
        const int x = x0 + lane;

        float sum = 0.0f;
#pragma unroll
        for (int t = 0; t < 9; ++t) {
            float oy, ox;
            if (t < 4)       { oy = av[9 + 2 * t] + obv[2 * t];
                               ox = av[10 + 2 * t] + obv[2 * t + 1]; }
            else if (t == 4) { oy = 0.0f; ox = 0.0f; }
            else             { oy = av[7 + 2 * t] + obv[2 * t - 2];
                               ox = av[8 + 2 * t] + obv[2 * t - 1]; }

            const float py = (float)(y - 1 + (t / 3)) + oy;
            const float px = (float)(x - 1 + (t % 3)) + ox;
            const float fy = floorf(py), fx = floorf(px);
            const float wy = py - fy, wx = px - fx;
            const int iy = (int)fy, ix = (int)fx;
            const int iy1 = iy + 1, ix1 = ix + 1;

            const bool vy0 = (unsigned)iy < (unsigned)HH;
            const bool vy1 = (unsigned)iy1 < (unsigned)HH;
            const bool vx0 = (unsigned)ix < (unsigned)WW;
            const bool vx1 = (unsigned)ix1 < (unsigned)WW;
            const float wy0 = 1.0f - wy, wx0 = 1.0f - wx;

            // tile-local coords; in-tile iff the 2x2 footprint is inside
            const int lyt = iy - (y0t - 4);
            const int lxt = ix - (x0 - 4);
            const bool in_tile = ((unsigned)lyt < 15u) & ((unsigned)lxt < 71u);

            float v00, v01, v10, v11;
            if (__all(in_tile)) {
                // wave-uniform fast path: pure LDS (scalar branch, no
                // divergent two-sided codegen)
                const float* tp = &ftile[lyt * 72 + lxt];
                v00 = tp[0];  v01 = tp[1];
                v10 = tp[72]; v11 = tp[73];
            } else {
                // whole-wave exact global clamp path (correct for all lanes)
                const int ry0 = min(max(iy, 0), HH - 1) * WW;
                const int ry1 = min(max(iy1, 0), HH - 1) * WW;
                const int cx0 = min(max(ix, 0), WW - 1);
                const int cx1 = min(max(ix1, 0), WW - 1);
                v00 = fb[ry0 + cx0]; v01 = fb[ry0 + cx1];
                v10 = fb[ry1 + cx0]; v11 = fb[ry1 + cx1];
            }

            float s = 0.0f;
            s = fmaf((vy0 & vx0) ? wy0 * wx0 : 0.0f, v00, s);
            s = fmaf((vy0 & vx1) ? wy0 * wx  : 0.0f, v01, s);
            s = fmaf((vy1 & vx0) ? wy  * wx0 : 0.0f, v10, s);
            s = fmaf((vy1 & vx1) ? wy  * wx  : 0.0f, v11, s);

            sum = fmaf(wg[t] * w3v[t], s, sum);
        }
        featNext[(size_t)b * HW + (size_t)y * WW + x] = fmaf(winv, sum, b3v);
    }
}

// ---------------------------------------------------------------------------
// Stage 1 of BN stats: per-block partial sums (float4-vectorized).
// ---------------------------------------------------------------------------
__global__ __launch_bounds__(256) void stats_part(
    const float* __restrict__ y0s, const float* __restrict__ y1s,
    const float* __restrict__ y2s, float* __restrict__ part)
{
    float a[9] = {0, 0, 0, 0, 0, 0, 0, 0, 0};
    const int n4 = NPIX / 4;
    const int stride = gridDim.x * 256;
    for (int i = blockIdx.x * 256 + threadIdx.x; i < n4; i += stride) {
        const float4 q0 = ((const float4*)y0s)[i];
        const float4 q1 = ((const float4*)y1s)[i];
        const float4 q2 = ((const float4*)y2s)[i];
        const float v0s[4] = {q0.x, q0.y, q0.z, q0.w};
        const float v1s[4] = {q1.x, q1.y, q1.z, q1.w};
        const float v2s[4] = {q2.x, q2.y, q2.z, q2.w};
#pragma unroll
        for (int j = 0; j < 4; ++j) {
            const float v0 = v0s[j], v1 = v1s[j], v2 = v2s[j];
            a[0] += v0; a[1] += v1; a[2] += v2;
            a[3] = fmaf(v0, v0, a[3]); a[4] = fmaf(v0, v1, a[4]);
            a[5] = fmaf(v0, v2, a[5]); a[6] = fmaf(v1, v1, a[6]);
            a[7] = fmaf(v1, v2, a[7]); a[8] = fmaf(v2, v2, a[8]);
        }
    }
    __shared__ float red[4][9];
    const int lane = threadIdx.x & 63, wv = threadIdx.x >> 6;
#pragma unroll
    for (int q = 0; q < 9; ++q) {
        float v = a[q];
        for (int o = 32; o; o >>= 1) v += __shfl_down(v, o, 64);
        if (lane == 0) red[wv][q] = v;
    }
    __syncthreads();
    if (threadIdx.x < 9) {
        const int q = threadIdx.x;
        part[blockIdx.x * 9 + q] = red[0][q] + red[1][q] + red[2][q] + red[3][q];
    }
}

// ---------------------------------------------------------------------------
// Stage 2: finalize per-channel BN scale/shift for sf = proj(y).
// ---------------------------------------------------------------------------
__global__ __launch_bounds__(256) void stats_final(
    const float* __restrict__ part, const float* __restrict__ proj_w,
    const float* __restrict__ bn_g, const float* __restrict__ bn_b,
    float* __restrict__ stats)
{
    float a[9] = {0, 0, 0, 0, 0, 0, 0, 0, 0};
    for (int i = threadIdx.x; i < NPART; i += 256) {
#pragma unroll
        for (int q = 0; q < 9; ++q) a[q] += part[i * 9 + q];
    }
    __shared__ float red[4][9];
    const int lane = threadIdx.x & 63, wv = threadIdx.x >> 6;
#pragma unroll
    for (int q = 0; q < 9; ++q) {
        float v = a[q];
        for (int o = 32; o; o >>= 1) v += __shfl_down(v, o, 64);
        if (lane == 0) red[wv][q] = v;
    }
    __syncthreads();
    if (threadIdx.x == 0) {
        float s[9];
#pragma unroll
        for (int q = 0; q < 9; ++q) s[q] = red[0][q] + red[1][q] + red[2][q] + red[3][q];
        const float invN = 1.0f / (float)NPIX;
        const float m0 = s[0] * invN, m1 = s[1] * invN, m2 = s[2] * invN;
        const float E00 = s[3] * invN, E01 = s[4] * invN, E02 = s[5] * invN;
        const float E11 = s[6] * invN, E12 = s[7] * invN, E22 = s[8] * invN;
#pragma unroll
        for (int c = 0; c < 6; ++c) {
            const float p0 = proj_w[c * 3], p1 = proj_w[c * 3 + 1], p2 = proj_w[c * 3 + 2];
            const float mu = p0 * m0 + p1 * m1 + p2 * m2;
            const float e2 = p0 * p0 * E00 + p1 * p1 * E11 + p2 * p2 * E22 +
                             2.0f * (p0 * p1 * E01 + p0 * p2 * E02 + p1 * p2 * E12);
            const float var = e2 - mu * mu;
            const float sc = bn_g[c] / sqrtf(var + 1e-5f);
            stats[c] = sc;
            stats[6 + c] = bn_b[c] - mu * sc;
        }
    }
}

// ---------------------------------------------------------------------------
// Fused head (unchanged): float4 phase-1, XCD-swizzled grid, a1/a2 in regs.
// ---------------------------------------------------------------------------
constexpr int HB_X = WW / 32;          // 38
constexpr int HB_Y = HH / 8;           // 30
constexpr int HB_N = HB_X * HB_Y * BATCH;   // 4560 (divisible by 8)
constexpr int HB_CHUNK = HB_N / 8;     // 570

__global__ __launch_bounds__(256, 4) void head_kernel(
    const float* __restrict__ y0s, const float* __restrict__ y1s,
    const float* __restrict__ y2s, const float* __restrict__ attn,
    const float* __restrict__ stats,   // scale[6], shift[6]
    const float* __restrict__ proj_w,
    const float* __restrict__ c0_w, const float* __restrict__ c0_b,
    const float* __restrict__ cs_w, const float* __restrict__ cs_b,
    const float* __restrict__ c1_w, const float* __restrict__ c1_b,
    const float* __restrict__ c2_w, const float* __restrict__ c2_b,
    const float* __restrict__ csq_w, const float* __restrict__ csq_b,
    const float* __restrict__ cv_w, const float* __restrict__ cv_b,
    float* __restrict__ out)
{
    __shared__ float ap[22][432];    // a1_pre, ext tile 12x36 (halo 2)
    __shared__ float aggs[2][340];   // agg, tile+halo1 10x34

    const int tid = threadIdx.x;
    const int bid = blockIdx.x;
    const int swz = (bid & 7) * HB_CHUNK + (bid >> 3);
    const int b = swz / (HB_X * HB_Y);
    const int rem0 = swz - b * (HB_X * HB_Y);
    const int by = rem0 / HB_X;
    const int bx = rem0 - by * HB_X;
    const int x0 = bx * 32;
    const int y0t = by * 8;

    // ---- phase 1: a1_pre over ext tile, float4 jobs ----
    for (int job = tid; job < 2040; job += 256) {
        int c = 0, rr, xc;
        bool isY;
        if (job < 1920) {
            c = job / 120;
            const int rem = job - c * 120;
            rr = rem / 10; xc = rem - rr * 10;
            isY = false;
        } else {
            const int rem = job - 1920;
            rr = rem / 10; xc = rem - rr * 10;
            isY = true;
        }
        const int gy = y0t + rr - 2;
        const int gxb = x0 - 4 + 4 * xc;           // 16B-aligned
        const bool gok = ((unsigned)gy < (unsigned)HH) &
                         ((unsigned)gxb <= (unsigned)(WW - 4));
        const size_t prow = (size_t)gy * WW + gxb;

        if (!isY) {
            float4 v4 = {0.f, 0.f, 0.f, 0.f};
            if (gok)
                v4 = *(const float4*)&attn[(size_t)b * 16 * HW + (size_t)c * HW + prow];
            const float w = c0_w[c], bb = c0_b[c];
            const float vin[4] = {v4.x, v4.y, v4.z, v4.w};
#pragma unroll
            for (int j = 0; j < 4; ++j) {
                const int exl = 4 * xc - 2 + j;
                if ((unsigned)exl < 36u)
                    ap[c][rr * 36 + exl] = gok ? fmaf(w, vin[j], bb) : 0.0f;
            }
        } else {
            float4 q0 = {0.f, 0.f, 0.f, 0.f}, q1 = q0, q2 = q0;
            if (gok) {
                const size_t p = (size_t)b * HW + prow;
                q0 = *(const float4*)&y0s[p];
                q1 = *(const float4*)&y1s[p];
                q2 = *(const float4*)&y2s[p];
            }
            const float v0s[4] = {q0.x, q0.y, q0.z, q0.w};
            const float v1s[4] = {q1.x, q1.y, q1.z, q1.w};
            const float v2s[4] = {q2.x, q2.y, q2.z, q2.w};
#pragma unroll
            for (int j = 0; j < 4; ++j) {
                const int exl = 4 * xc - 2 + j;
                if ((unsigned)exl >= 36u) continue;
#pragma unroll
                for (int q = 0; q < 6; ++q) {
                    float v = 0.0f;
                    if (gok) {
                        const float sraw = proj_w[q * 3] * v0s[j] +
                                           proj_w[q * 3 + 1] * v1s[j] +
                                           proj_w[q * 3 + 2] * v2s[j];
                        float sf = fmaf(stats[q], sraw, stats[6 + q]);
                        sf = sf > 0.0f ? sf : 0.2f * sf;
                        v = fmaf(c0_w[16 + q], sf, c0_b[16 + q]);
                    }
                    ap[16 + q][rr * 36 + exl] = v;
                }
            }
        }
    }
    __syncthreads();

    auto compute_px = [&](int ay, int ax, float* a1, float* a2) {
        const int ey = ay + 1, ex = ax + 1;   // ext coords
#pragma unroll
        for (int j = 0; j < 11; ++j) { a1[j] = c1_b[j]; a2[j] = c2_b[j]; }
#pragma unroll
        for (int c = 0; c < 22; ++c) {
            float dw = cs_b[c];
            float ctr = 0.0f;
#pragma unroll
            for (int t = 0; t < 9; ++t) {
                const float av = ap[c][(ey + t / 3 - 1) * 36 + (ex + t % 3 - 1)];
                dw = fmaf(cs_w[c * 9 + t], av, dw);
                if (t == 4) ctr = av;
            }
#pragma unroll
            for (int j = 0; j < 11; ++j) {
                a1[j] = fmaf(c1_w[j * 22 + c], ctr, a1[j]);
                a2[j] = fmaf(c2_w[j * 22 + c], dw, a2[j]);
            }
        }
    };

    // ---- phase 2a: ring jobs (84 halo pixels of the 10x34 agg region) ----
    if (tid < 84) {
        int ay, ax;
        if (tid < 34)      { ay = 0; ax = tid; }
        else if (tid < 68) { ay = 9; ax = tid - 34; }
        else { const int s = tid - 68; ay = 1 + (s >> 1); ax = (s & 1) ? 33 : 0; }
        const int gy = y0t + ay - 1, gx = x0 + ax - 1;
        float m0 = 0.0f, m1 = 0.0f;
        if (((unsigned)gy < (unsigned)HH) & ((unsigned)gx < (unsigned)WW)) {
            float a1h[11], a2h[11];
            compute_px(ay, ax, a1h, a2h);
            float s = 0.0f, mx = -INFINITY;
#pragma unroll
            for (int j = 0; j < 11; ++j) {
                s += a1h[j] + a2h[j];
                mx = fmaxf(mx, fmaxf(a1h[j], a2h[j]));
            }
            m0 = s * (1.0f / 22.0f);
            m1 = mx;
        }
        aggs[0][ay * 34 + ax] = m0;
        aggs[1][ay * 34 + ax] = m1;
    }

    // ---- phase 2b: center pixel, keep a1/a2 in registers ----
    const int ty = tid >> 5, tx = tid & 31;
    const int ay = ty + 1, ax = tx + 1;
    float a1[11], a2[11];
    compute_px(ay, ax, a1, a2);
    {
        float s = 0.0f, mx = -INFINITY;
#pragma unroll
        for (int j = 0; j < 11; ++j) {
            s += a1[j] + a2[j];
            mx = fmaxf(mx, fmaxf(a1[j], a2[j]));
        }
        aggs[0][ay * 34 + ax] = s * (1.0f / 22.0f);
        aggs[1][ay * 34 + ax] = mx;
    }
    __syncthreads();

    // ---- phase 3: sigmoid gate + cv + final dot with y ----
    float z0 = csq_b[0], z1 = csq_b[1];
#pragma unroll
    for (int t = 0; t < 9; ++t) {
        const int ai = (ay + t / 3 - 1) * 34 + (ax + t % 3 - 1);
        const float g0 = aggs[0][ai], g1 = aggs[1][ai];
        z0 = fmaf(csq_w[t], g0, fmaf(csq_w[9 + t], g1, z0));
        z1 = fmaf(csq_w[18 + t], g0, fmaf(csq_w[27 + t], g1, z1));
    }
    const float s0 = 1.0f / (1.0f + __expf(-z0));
    const float s1 = 1.0f / (1.0f + __expf(-z1));
    float v0 = cv_b[0], v1 = cv_b[1], v2 = cv_b[2];
#pragma unroll
    for (int j = 0; j < 11; ++j) {
        const float av = a1[j] * s0 + a2[j] * s1;
        v0 = fmaf(cv_w[j], av, v0);
        v1 = fmaf(cv_w[11 + j], av, v1);
        v2 = fmaf(cv_w[22 + j], av, v2);
    }
    const size_t p = (size_t)b * HW + (size_t)(y0t + ty) * WW + (x0 + tx);
    out[p] = y0s[p] * v0 + y1s[p] * v1 + y2s[p] * v2;
}

// ---------------------------------------------------------------------------
extern "C" void kernel_launch(void* const* d_in, const int* in_sizes, int n_in,
                              void* d_out, int out_size, void* d_ws, size_t ws_size,
                              hipStream_t stream)
{
    (void)in_sizes; (void)n_in; (void)out_size; (void)ws_size;
    const float* feat_init = (const float*)d_in[0];
    const float* guidance  = (const float*)d_in[1];
    const float* attn      = (const float*)d_in[2];
    const float* aff_w_w   = (const float*)d_in[4];
    const float* aff_w_b   = (const float*)d_in[5];
    const float* aff_o_w   = (const float*)d_in[6];
    const float* aff_o_b   = (const float*)d_in[7];
    const float* w3        = (const float*)d_in[8];
    const float* b3        = (const float*)d_in[9];
    const float* proj_w    = (const float*)d_in[10];
    const float* bn_g      = (const float*)d_in[11];
    const float* bn_b      = (const float*)d_in[12];
    const float* c0_w      = (const float*)d_in[13];
    const float* c0_b      = (const float*)d_in[14];
    const float* cs_w      = (const float*)d_in[15];
    const float* cs_b      = (const float*)d_in[16];
    const float* c1_w      = (const float*)d_in[17];
    const float* c1_b      = (const float*)d_in[18];
    const float* c2_w      = (const float*)d_in[19];
    const float* c2_b      = (const float*)d_in[20];
    const float* csq_w     = (const float*)d_in[21];
    const float* csq_b     = (const float*)d_in[22];
    const float* cv_w      = (const float*)d_in[23];
    const float* cv_b      = (const float*)d_in[24];

    float* ws = (float*)d_ws;
    float* slot[5];
    for (int i = 0; i < 5; ++i) slot[i] = ws + (size_t)i * NPIX;
    float* part  = ws + (size_t)5 * NPIX;
    float* stats = part + (size_t)9 * NPART;

    const dim3 blk(256);
    const dim3 gp(WW / 64, HH / 8, BATCH);

    // propagation chain; keep feats[3],[4],[5] in slots 2,3,4
    const int dst_ids[PROP] = {0, 1, 0, 2, 3, 4};
    const float* src = feat_init;
    for (int k = 0; k < PROP; ++k) {
        float* dst = slot[dst_ids[k]];
        prop_kernel<<<gp, blk, 0, stream>>>(
            src, guidance + (size_t)8 * k * HW,
            aff_w_w + (size_t)k * 648, aff_w_b + (size_t)k * 9,
            aff_o_w + (size_t)k * 1152, aff_o_b + (size_t)k * 16,
            w3, b3, dst);
        src = dst;
    }

    stats_part<<<dim3(NPART), blk, 0, stream>>>(slot[2], slot[3], slot[4], part);
    stats_final<<<dim3(1), blk, 0, stream>>>(part, proj_w, bn_g, bn_b, stats);

    head_kernel<<<dim3(HB_N), blk, 0, stream>>>(
        slot[2], slot[3], slot[4], attn, stats, proj_w,
        c0_w, c0_b, cs_w, cs_b, c1_w, c1_b, c2_w, c2_b,
        csq_w, csq_b, cv_w, cv_b, (float*)d_out);
}

// Round 10
// 628.789 us; speedup vs baseline: 2.1451x; 1.4412x over previous
//
#include <hip/hip_runtime.h>
#include <hip/hip_bf16.h>
#include <math.h>

#define HH 240
#define WW 1216
#define BATCH 4
#define PROP 6
constexpr int HW = HH * WW;            // 291,840
constexpr int NPIX = BATCH * HW;       // 1,167,360
constexpr int NPART = 1024;

typedef short short8 __attribute__((ext_vector_type(8)));
typedef float floatx4 __attribute__((ext_vector_type(4)));

__device__ __forceinline__ unsigned short f2bf(float f) {
    unsigned int u = __float_as_uint(f);
    unsigned int r = (u + 0x7FFFu + ((u >> 16) & 1u)) >> 16;
    return (unsigned short)r;
}
__device__ __forceinline__ float bf2f(unsigned short h) {
    return __uint_as_float(((unsigned int)h) << 16);
}

// LDS layout (bytes):
//   gs16   [8][10][66] u16 (bf16-hi guidance)  @ 0     : 10560
//   region2 @ 10560 (aliased, lifetimes disjoint):
//     wst    [32][96] f32 @ 10560 : 12288 (dead after A-frag build)
//     offtab [96] u32     @ 22848 : 384   (dead after cvaddr build)
//     ct     4 waves x [64][25] u16 (bf16) @ 10560 : 12800 (after sync2)
constexpr int CT_STRIDE = 25;          // u16 elems; ~2-way bank alias = free
constexpr int SMEM_BYTES = 23360;      // -> 6 blocks/CU (160K/23.4K)

// ---------------------------------------------------------------------------
// Propagation v9 = v6 structure (pure-global clamp gather epilogue — the
// LDS-tile gather variants v7/v8 spilled ~190MB scratch) + ct transpose
// buffer in bf16-u16 to cut LDS 37.6->23.4 KB (4->6 blocks/CU) for latency
// hiding on the 36 scattered bilinear loads per pixel.
// ---------------------------------------------------------------------------
__global__ __launch_bounds__(256, 4) void prop_kernel(
    const float* __restrict__ featPrev,   // [B][HW]
    const float* __restrict__ gbase,      // guidance + 8k*HW; batch stride 48*HW
    const float* __restrict__ aw,         // [9][8][3][3]
    const float* __restrict__ ab,         // [9]
    const float* __restrict__ ow,         // [16][8][3][3]
    const float* __restrict__ ob,         // [16]
    const float* __restrict__ w3,         // [9]
    const float* __restrict__ b3,         // [1]
    float* __restrict__ featNext)         // [B][HW]
{
    __shared__ __attribute__((aligned(16))) unsigned char smem[SMEM_BYTES];
    unsigned short* gs16 = (unsigned short*)smem;
    float*    wst    = (float*)(smem + 10560);
    uint32_t* offtab = (uint32_t*)(smem + 22848);
    unsigned short* ctb = (unsigned short*)(smem + 10560);

    const int tid = threadIdx.x;
    const int x0 = blockIdx.x * 64;
    const int y0t = blockIdx.y * 8;
    const int b = blockIdx.z;
    const float* gb = gbase + (size_t)b * (48 * HW);
    const float* fb = featPrev + (size_t)b * HW;

    // ---- stage guidance ext tile as bf16-hi u16 (zero-pad OOB) ----
    for (int idx = tid; idx < 5280; idx += 256) {
        const int c = idx / 660, rem = idx - c * 660;
        const int row = rem / 66, col = rem - row * 66;
        const int gy = y0t + row - 1, gx = x0 + col - 1;
        float v = 0.0f;
        if (((unsigned)gy < (unsigned)HH) & ((unsigned)gx < (unsigned)WW))
            v = gb[c * HW + gy * WW + gx];
        gs16[idx] = f2bf(v);
    }
    // ---- stage weight matrix [o(32,pad)][k(96,pad)] fp32, zeros on pad ----
    for (int idx = tid; idx < 3072; idx += 256) {
        const int o = idx / 96, k = idx - o * 96;
        float v = 0.0f;
        if (o < 25 && k < 72) {
            const int c = k / 9, t = k - 9 * c;
            v = (o < 9) ? aw[(o * 8 + c) * 9 + t] : ow[((o - 9) * 8 + c) * 9 + t];
        }
        wst[idx] = v;
    }
    // ---- offtab[s][e][g]: gs16 element-offset of (c, dy, dx) for that k ----
    if (tid < 96) {
        const int s = tid >> 5, rem = tid & 31, e = rem >> 2, gq = rem & 3;
        const int k = s * 32 + gq * 8 + e;
        uint32_t off = 0;
        if (k < 72) {
            const int c = k / 9, t = k - 9 * c, dy = t / 3, dx = t - 3 * dy;
            off = (uint32_t)(c * 660 + dy * 66 + dx);
        }
        offtab[tid] = off;
    }
    __syncthreads();

    const int lane = tid & 63, wid = tid >> 6;
    const int grp = lane >> 4, l15 = lane & 15;

    // ---- A fragments: lane supplies A[m = l15][k = s*32 + grp*8 + e] ----
    short8 Ah0[3], Ah1[3], Al0[3], Al1[3];
    {
        const int kb = grp * 8;
#pragma unroll
        for (int s = 0; s < 3; ++s) {
            const float* wp0 = &wst[l15 * 96 + s * 32 + kb];
            const float* wp1 = &wst[(16 + l15) * 96 + s * 32 + kb];
            short8 h0, l0, h1, l1;
#pragma unroll
            for (int e = 0; e < 8; ++e) {
                const float v0 = wp0[e];
                const unsigned short hb0 = f2bf(v0);
                h0[e] = (short)hb0;
                l0[e] = (short)f2bf(v0 - bf2f(hb0));
                const float v1 = wp1[e];
                const unsigned short hb1 = f2bf(v1);
                h1[e] = (short)hb1;
                l1[e] = (short)f2bf(v1 - bf2f(hb1));
            }
            Ah0[s] = h0; Al0[s] = l0; Ah1[s] = h1; Al1[s] = l1;
        }
    }

    // ---- per-lane B-read byte addresses (24) ----
    uint32_t cvaddr[3][8];
#pragma unroll
    for (int s = 0; s < 3; ++s)
#pragma unroll
        for (int e = 0; e < 8; ++e)
            cvaddr[s][e] = (offtab[s * 32 + e * 4 + grp] +
                            (uint32_t)(wid * 132 + l15)) * 2u;

    // ---- uniform epilogue params (s_loads) ----
    float abv[9], w3v[9], obv[16];
#pragma unroll
    for (int t = 0; t < 9; ++t) { abv[t] = ab[t]; w3v[t] = w3[t]; }
#pragma unroll
    for (int o = 0; o < 16; ++o) obv[o] = ob[o];
    const float b3v = b3[0];

    __syncthreads();   // all waves done reading wst/offtab before ct reuse

    unsigned short* ct = ctb + wid * (64 * CT_STRIDE);
    const int ybase = y0t + wid * 2;
    const unsigned char* gsB = (const unsigned char*)gs16;

#pragma unroll 1
    for (int r = 0; r < 2; ++r) {
        const int y = ybase + r;
        // ---- 4 MFMA chunks back-to-back: conv outputs for the 64-px row ----
#pragma unroll
        for (int ch = 0; ch < 4; ++ch) {
            floatx4 acc0 = {0.f, 0.f, 0.f, 0.f};
            floatx4 acc1 = {0.f, 0.f, 0.f, 0.f};
#pragma unroll
            for (int s = 0; s < 3; ++s) {
                uint32_t ev[8];
#pragma unroll
                for (int e = 0; e < 8; ++e)
                    ev[e] = *(const unsigned short*)(gsB + cvaddr[s][e] +
                                                     (r * 66 + ch * 16) * 2);
                union { uint32_t u[4]; short8 v; } bh;
#pragma unroll
                for (int i = 0; i < 4; ++i)
                    bh.u[i] = ev[2 * i] | (ev[2 * i + 1] << 16);
                acc0 = __builtin_amdgcn_mfma_f32_16x16x32_bf16(Ah0[s], bh.v, acc0, 0, 0, 0);
                acc1 = __builtin_amdgcn_mfma_f32_16x16x32_bf16(Ah1[s], bh.v, acc1, 0, 0, 0);
                acc0 = __builtin_amdgcn_mfma_f32_16x16x32_bf16(Al0[s], bh.v, acc0, 0, 0, 0);
                acc1 = __builtin_amdgcn_mfma_f32_16x16x32_bf16(Al1[s], bh.v, acc1, 0, 0, 0);
            }
            // C layout: col(px) = l15, row(o) = grp*4 + i  (+16 for Mtile1)
            const int pxb = (ch * 16 + l15) * CT_STRIDE;
#pragma unroll
            for (int i = 0; i < 4; ++i) {
                ct[pxb + grp * 4 + i] = f2bf(acc0[i]);
                if (grp * 4 + i < 9)                    // only o=16..24 valid
                    ct[pxb + 16 + grp * 4 + i] = f2bf(acc1[i]);
            }
        }

        // ---- epilogue: lane owns pixel x0+lane of row y ----
        const unsigned short* cb = ct + lane * CT_STRIDE;
        float av[25];
#pragma unroll
        for (int o = 0; o < 25; ++o) av[o] = bf2f(cb[o]);

        float wg[9], wsum = 1e-8f;
#pragma unroll
        for (int t = 0; t < 9; ++t) {
            const float s = 1.0f / (1.0f + __expf(-(av[t] + abv[t])));
            wg[t] = s;
            wsum += s;
        }
        const float winv = 1.0f / wsum;
        const int x = x0 + lane;

        float sum = 0.0f;
#pragma unroll
        for (int t = 0; t < 9; ++t) {
            float oy, ox;
            if (t < 4)       { oy = av[9 + 2 * t] + obv[2 * t];
                               ox = av[10 + 2 * t] + obv[2 * t + 1]; }
            else if (t == 4) { oy = 0.0f; ox = 0.0f; }
            else             { oy = av[7 + 2 * t] + obv[2 * t - 2];
                               ox = av[8 + 2 * t] + obv[2 * t - 1]; }

            const float py = (float)(y - 1 + (t / 3)) + oy;
            const float px = (float)(x - 1 + (t % 3)) + ox;
            const float fy = floorf(py), fx = floorf(px);
            const float wy = py - fy, wx = px - fx;
            const int iy = (int)fy, ix = (int)fx;
            const int iy1 = iy + 1, ix1 = ix + 1;

            const int ry0 = min(max(iy, 0), HH - 1) * WW;
            const int ry1 = min(max(iy1, 0), HH - 1) * WW;
            const int cx0 = min(max(ix, 0), WW - 1);
            const int cx1 = min(max(ix1, 0), WW - 1);
            const float v00 = fb[ry0 + cx0], v01 = fb[ry0 + cx1];
            const float v10 = fb[ry1 + cx0], v11 = fb[ry1 + cx1];

            const bool vy0 = (unsigned)iy < (unsigned)HH;
            const bool vy1 = (unsigned)iy1 < (unsigned)HH;
            const bool vx0 = (unsigned)ix < (unsigned)WW;
            const bool vx1 = (unsigned)ix1 < (unsigned)WW;
            const float wy0 = 1.0f - wy, wx0 = 1.0f - wx;

            float s = 0.0f;
            s = fmaf((vy0 & vx0) ? wy0 * wx0 : 0.0f, v00, s);
            s = fmaf((vy0 & vx1) ? wy0 * wx  : 0.0f, v01, s);
            s = fmaf((vy1 & vx0) ? wy  * wx0 : 0.0f, v10, s);
            s = fmaf((vy1 & vx1) ? wy  * wx  : 0.0f, v11, s);

            sum = fmaf(wg[t] * w3v[t], s, sum);
        }
        featNext[(size_t)b * HW + (size_t)y * WW + x] = fmaf(winv, sum, b3v);
    }
}

// ---------------------------------------------------------------------------
// Stage 1 of BN stats: per-block partial sums (float4-vectorized).
// ---------------------------------------------------------------------------
__global__ __launch_bounds__(256) void stats_part(
    const float* __restrict__ y0s, const float* __restrict__ y1s,
    const float* __restrict__ y2s, float* __restrict__ part)
{
    float a[9] = {0, 0, 0, 0, 0, 0, 0, 0, 0};
    const int n4 = NPIX / 4;
    const int stride = gridDim.x * 256;
    for (int i = blockIdx.x * 256 + threadIdx.x; i < n4; i += stride) {
        const float4 q0 = ((const float4*)y0s)[i];
        const float4 q1 = ((const float4*)y1s)[i];
        const float4 q2 = ((const float4*)y2s)[i];
        const float v0s[4] = {q0.x, q0.y, q0.z, q0.w};
        const float v1s[4] = {q1.x, q1.y, q1.z, q1.w};
        const float v2s[4] = {q2.x, q2.y, q2.z, q2.w};
#pragma unroll
        for (int j = 0; j < 4; ++j) {
            const float v0 = v0s[j], v1 = v1s[j], v2 = v2s[j];
            a[0] += v0; a[1] += v1; a[2] += v2;
            a[3] = fmaf(v0, v0, a[3]); a[4] = fmaf(v0, v1, a[4]);
            a[5] = fmaf(v0, v2, a[5]); a[6] = fmaf(v1, v1, a[6]);
            a[7] = fmaf(v1, v2, a[7]); a[8] = fmaf(v2, v2, a[8]);
        }
    }
    __shared__ float red[4][9];
    const int lane = threadIdx.x & 63, wv = threadIdx.x >> 6;
#pragma unroll
    for (int q = 0; q < 9; ++q) {
        float v = a[q];
        for (int o = 32; o; o >>= 1) v += __shfl_down(v, o, 64);
        if (lane == 0) red[wv][q] = v;
    }
    __syncthreads();
    if (threadIdx.x < 9) {
        const int q = threadIdx.x;
        part[blockIdx.x * 9 + q] = red[0][q] + red[1][q] + red[2][q] + red[3][q];
    }
}

// ---------------------------------------------------------------------------
// Stage 2: finalize per-channel BN scale/shift for sf = proj(y).
// ---------------------------------------------------------------------------
__global__ __launch_bounds__(256) void stats_final(
    const float* __restrict__ part, const float* __restrict__ proj_w,
    const float* __restrict__ bn_g, const float* __restrict__ bn_b,
    float* __restrict__ stats)
{
    float a[9] = {0, 0, 0, 0, 0, 0, 0, 0, 0};
    for (int i = threadIdx.x; i < NPART; i += 256) {
#pragma unroll
        for (int q = 0; q < 9; ++q) a[q] += part[i * 9 + q];
    }
    __shared__ float red[4][9];
    const int lane = threadIdx.x & 63, wv = threadIdx.x >> 6;
#pragma unroll
    for (int q = 0; q < 9; ++q) {
        float v = a[q];
        for (int o = 32; o; o >>= 1) v += __shfl_down(v, o, 64);
        if (lane == 0) red[wv][q] = v;
    }
    __syncthreads();
    if (threadIdx.x == 0) {
        float s[9];
#pragma unroll
        for (int q = 0; q < 9; ++q) s[q] = red[0][q] + red[1][q] + red[2][q] + red[3][q];
        const float invN = 1.0f / (float)NPIX;
        const float m0 = s[0] * invN, m1 = s[1] * invN, m2 = s[2] * invN;
        const float E00 = s[3] * invN, E01 = s[4] * invN, E02 = s[5] * invN;
        const float E11 = s[6] * invN, E12 = s[7] * invN, E22 = s[8] * invN;
#pragma unroll
        for (int c = 0; c < 6; ++c) {
            const float p0 = proj_w[c * 3], p1 = proj_w[c * 3 + 1], p2 = proj_w[c * 3 + 2];
            const float mu = p0 * m0 + p1 * m1 + p2 * m2;
            const float e2 = p0 * p0 * E00 + p1 * p1 * E11 + p2 * p2 * E22 +
                             2.0f * (p0 * p1 * E01 + p0 * p2 * E02 + p1 * p2 * E12);
            const float var = e2 - mu * mu;
            const float sc = bn_g[c] / sqrtf(var + 1e-5f);
            stats[c] = sc;
            stats[6 + c] = bn_b[c] - mu * sc;
        }
    }
}

// ---------------------------------------------------------------------------
// Fused head (unchanged): float4 phase-1, XCD-swizzled grid, a1/a2 in regs.
// ---------------------------------------------------------------------------
constexpr int HB_X = WW / 32;          // 38
constexpr int HB_Y = HH / 8;           // 30
constexpr int HB_N = HB_X * HB_Y * BATCH;   // 4560 (divisible by 8)
constexpr int HB_CHUNK = HB_N / 8;     // 570

__global__ __launch_bounds__(256, 4) void head_kernel(
    const float* __restrict__ y0s, const float* __restrict__ y1s,
    const float* __restrict__ y2s, const float* __restrict__ attn,
    const float* __restrict__ stats,   // scale[6], shift[6]
    const float* __restrict__ proj_w,
    const float* __restrict__ c0_w, const float* __restrict__ c0_b,
    const float* __restrict__ cs_w, const float* __restrict__ cs_b,
    const float* __restrict__ c1_w, const float* __restrict__ c1_b,
    const float* __restrict__ c2_w, const float* __restrict__ c2_b,
    const float* __restrict__ csq_w, const float* __restrict__ csq_b,
    const float* __restrict__ cv_w, const float* __restrict__ cv_b,
    float* __restrict__ out)
{
    __shared__ float ap[22][432];    // a1_pre, ext tile 12x36 (halo 2)
    __shared__ float aggs[2][340];   // agg, tile+halo1 10x34

    const int tid = threadIdx.x;
    const int bid = blockIdx.x;
    const int swz = (bid & 7) * HB_CHUNK + (bid >> 3);
    const int b = swz / (HB_X * HB_Y);
    const int rem0 = swz - b * (HB_X * HB_Y);
    const int by = rem0 / HB_X;
    const int bx = rem0 - by * HB_X;
    const int x0 = bx * 32;
    const int y0t = by * 8;

    // ---- phase 1: a1_pre over ext tile, float4 jobs ----
    for (int job = tid; job < 2040; job += 256) {
        int c = 0, rr, xc;
        bool isY;
        if (job < 1920) {
            c = job / 120;
            const int rem = job - c * 120;
            rr = rem / 10; xc = rem - rr * 10;
            isY = false;
        } else {
            const int rem = job - 1920;
            rr = rem / 10; xc = rem - rr * 10;
            isY = true;
        }
        const int gy = y0t + rr - 2;
        const int gxb = x0 - 4 + 4 * xc;           // 16B-aligned
        const bool gok = ((unsigned)gy < (unsigned)HH) &
                         ((unsigned)gxb <= (unsigned)(WW - 4));
        const size_t prow = (size_t)gy * WW + gxb;

        if (!isY) {
            float4 v4 = {0.f, 0.f, 0.f, 0.f};
            if (gok)
                v4 = *(const float4*)&attn[(size_t)b * 16 * HW + (size_t)c * HW + prow];
            const float w = c0_w[c], bb = c0_b[c];
            const float vin[4] = {v4.x, v4.y, v4.z, v4.w};
#pragma unroll
            for (int j = 0; j < 4; ++j) {
                const int exl = 4 * xc - 2 + j;
                if ((unsigned)exl < 36u)
                    ap[c][rr * 36 + exl] = gok ? fmaf(w, vin[j], bb) : 0.0f;
            }
        } else {
            float4 q0 = {0.f, 0.f, 0.f, 0.f}, q1 = q0, q2 = q0;
            if (gok) {
                const size_t p = (size_t)b * HW + prow;
                q0 = *(const float4*)&y0s[p];
                q1 = *(const float4*)&y1s[p];
                q2 = *(const float4*)&y2s[p];
            }
            const float v0s[4] = {q0.x, q0.y, q0.z, q0.w};
            const float v1s[4] = {q1.x, q1.y, q1.z, q1.w};
            const float v2s[4] = {q2.x, q2.y, q2.z, q2.w};
#pragma unroll
            for (int j = 0; j < 4; ++j) {
                const int exl = 4 * xc - 2 + j;
                if ((unsigned)exl >= 36u) continue;
#pragma unroll
                for (int q = 0; q < 6; ++q) {
                    float v = 0.0f;
                    if (gok) {
                        const float sraw = proj_w[q * 3] * v0s[j] +
                                           proj_w[q * 3 + 1] * v1s[j] +
                                           proj_w[q * 3 + 2] * v2s[j];
                        float sf = fmaf(stats[q], sraw, stats[6 + q]);
                        sf = sf > 0.0f ? sf : 0.2f * sf;
                        v = fmaf(c0_w[16 + q], sf, c0_b[16 + q]);
                    }
                    ap[16 + q][rr * 36 + exl] = v;
                }
            }
        }
    }
    __syncthreads();

    auto compute_px = [&](int ay, int ax, float* a1, float* a2) {
        const int ey = ay + 1, ex = ax + 1;   // ext coords
#pragma unroll
        for (int j = 0; j < 11; ++j) { a1[j] = c1_b[j]; a2[j] = c2_b[j]; }
#pragma unroll
        for (int c = 0; c < 22; ++c) {
            float dw = cs_b[c];
            float ctr = 0.0f;
#pragma unroll
            for (int t = 0; t < 9; ++t) {
                const float av = ap[c][(ey + t / 3 - 1) * 36 + (ex + t % 3 - 1)];
                dw = fmaf(cs_w[c * 9 + t], av, dw);
                if (t == 4) ctr = av;
            }
#pragma unroll
            for (int j = 0; j < 11; ++j) {
                a1[j] = fmaf(c1_w[j * 22 + c], ctr, a1[j]);
                a2[j] = fmaf(c2_w[j * 22 + c], dw, a2[j]);
            }
        }
    };

    // ---- phase 2a: ring jobs (84 halo pixels of the 10x34 agg region) ----
    if (tid < 84) {
        int ay, ax;
        if (tid < 34)      { ay = 0; ax = tid; }
        else if (tid < 68) { ay = 9; ax = tid - 34; }
        else { const int s = tid - 68; ay = 1 + (s >> 1); ax = (s & 1) ? 33 : 0; }
        const int gy = y0t + ay - 1, gx = x0 + ax - 1;
        float m0 = 0.0f, m1 = 0.0f;
        if (((unsigned)gy < (unsigned)HH) & ((unsigned)gx < (unsigned)WW)) {
            float a1h[11], a2h[11];
            compute_px(ay, ax, a1h, a2h);
            float s = 0.0f, mx = -INFINITY;
#pragma unroll
            for (int j = 0; j < 11; ++j) {
                s += a1h[j] + a2h[j];
                mx = fmaxf(mx, fmaxf(a1h[j], a2h[j]));
            }
            m0 = s * (1.0f / 22.0f);
            m1 = mx;
        }
        aggs[0][ay * 34 + ax] = m0;
        aggs[1][ay * 34 + ax] = m1;
    }

    // ---- phase 2b: center pixel, keep a1/a2 in registers ----
    const int ty = tid >> 5, tx = tid & 31;
    const int ay = ty + 1, ax = tx + 1;
    float a1[11], a2[11];
    compute_px(ay, ax, a1, a2);
    {
        float s = 0.0f, mx = -INFINITY;
#pragma unroll
        for (int j = 0; j < 11; ++j) {
            s += a1[j] + a2[j];
            mx = fmaxf(mx, fmaxf(a1[j], a2[j]));
        }
        aggs[0][ay * 34 + ax] = s * (1.0f / 22.0f);
        aggs[1][ay * 34 + ax] = mx;
    }
    __syncthreads();

    // ---- phase 3: sigmoid gate + cv + final dot with y ----
    float z0 = csq_b[0], z1 = csq_b[1];
#pragma unroll
    for (int t = 0; t < 9; ++t) {
        const int ai = (ay + t / 3 - 1) * 34 + (ax + t % 3 - 1);
        const float g0 = aggs[0][ai], g1 = aggs[1][ai];
        z0 = fmaf(csq_w[t], g0, fmaf(csq_w[9 + t], g1, z0));
        z1 = fmaf(csq_w[18 + t], g0, fmaf(csq_w[27 + t], g1, z1));
    }
    const float s0 = 1.0f / (1.0f + __expf(-z0));
    const float s1 = 1.0f / (1.0f + __expf(-z1));
    float v0 = cv_b[0], v1 = cv_b[1], v2 = cv_b[2];
#pragma unroll
    for (int j = 0; j < 11; ++j) {
        const float av = a1[j] * s0 + a2[j] * s1;
        v0 = fmaf(cv_w[j], av, v0);
        v1 = fmaf(cv_w[11 + j], av, v1);
        v2 = fmaf(cv_w[22 + j], av, v2);
    }
    const size_t p = (size_t)b * HW + (size_t)(y0t + ty) * WW + (x0 + tx);
    out[p] = y0s[p] * v0 + y1s[p] * v1 + y2s[p] * v2;
}

// ---------------------------------------------------------------------------
extern "C" void kernel_launch(void* const* d_in, const int* in_sizes, int n_in,
                              void* d_out, int out_size, void* d_ws, size_t ws_size,
                              hipStream_t stream)
{
    (void)in_sizes; (void)n_in; (void)out_size; (void)ws_size;
    const float* feat_init = (const float*)d_in[0];
    const float* guidance  = (const float*)d_in[1];
    const float* attn      = (const float*)d_in[2];
    const float* aff_w_w   = (const float*)d_in[4];
    const float* aff_w_b   = (const float*)d_in[5];
    const float* aff_o_w   = (const float*)d_in[6];
    const float* aff_o_b   = (const float*)d_in[7];
    const float* w3        = (const float*)d_in[8];
    const float* b3        = (const float*)d_in[9];
    const float* proj_w    = (const float*)d_in[10];
    const float* bn_g      = (const float*)d_in[11];
    const float* bn_b      = (const float*)d_in[12];
    const float* c0_w      = (const float*)d_in[13];
    const float* c0_b      = (const float*)d_in[14];
    const float* cs_w      = (const float*)d_in[15];
    const float* cs_b      = (const float*)d_in[16];
    const float* c1_w      = (const float*)d_in[17];
    const float* c1_b      = (const float*)d_in[18];
    const float* c2_w      = (const float*)d_in[19];
    const float* c2_b      = (const float*)d_in[20];
    const float* csq_w     = (const float*)d_in[21];
    const float* csq_b     = (const float*)d_in[22];
    const float* cv_w      = (const float*)d_in[23];
    const float* cv_b      = (const float*)d_in[24];

    float* ws = (float*)d_ws;
    float* slot[5];
    for (int i = 0; i < 5; ++i) slot[i] = ws + (size_t)i * NPIX;
    float* part  = ws + (size_t)5 * NPIX;
    float* stats = part + (size_t)9 * NPART;

    const dim3 blk(256);
    const dim3 gp(WW / 64, HH / 8, BATCH);

    // propagation chain; keep feats[3],[4],[5] in slots 2,3,4
    const int dst_ids[PROP] = {0, 1, 0, 2, 3, 4};
    const float* src = feat_init;
    for (int k = 0; k < PROP; ++k) {
        float* dst = slot[dst_ids[k]];
        prop_kernel<<<gp, blk, 0, stream>>>(
            src, guidance + (size_t)8 * k * HW,
            aff_w_w + (size_t)k * 648, aff_w_b + (size_t)k * 9,
            aff_o_w + (size_t)k * 1152, aff_o_b + (size_t)k * 16,
            w3, b3, dst);
        src = dst;
    }

    stats_part<<<dim3(NPART), blk, 0, stream>>>(slot[2], slot[3], slot[4], part);
    stats_final<<<dim3(1), blk, 0, stream>>>(part, proj_w, bn_g, bn_b, stats);

    head_kernel<<<dim3(HB_N), blk, 0, stream>>>(
        slot[2], slot[3], slot[4], attn, stats, proj_w,
        c0_w, c0_b, cs_w, cs_b, c1_w, c1_b, c2_w, c2_b,
        csq_w, csq_b, cv_w, cv_b, (float*)d_out);
}